// Round 1
// baseline (8169.632 us; speedup 1.0000x reference)
//
#include <hip/hip_runtime.h>
#include <hip/hip_bf16.h>

#define BB 16
#define CC 512
#define HWP 4096
#define DD 256
#define NPIX 65536
#define INV_SQRT_C 0.04419417382415922f

// ---------------- ws layout (floats) ----------------
// G    : 0        (65536)   256x256 Gram of A, chol'd in place (upper = U)
// Rt   : 65536    (65536)   Rinv transposed: Rt[j][l] = Rinv[l][j]
// Q    : 131072   (131072)  512x256 row-major Q[c][d]
// Qst  : 262144   (131072)  256x512 Qst[d][c] = Q[c][d]*INV_SQRT_C
// S    : 393216   (262144)  512x512 Gram of x
// xbar : 655360   (512)
// Wgf  : 655872   (262144)
// bgf  : 918016   (512)
// Wcf  : 918528   (262144)
// bcf  : 1180672  (512)
// gvec : 1181184  (8192)    16x512 sigmoid gate
// gpart: 1189376  (131072)  [16b][16slab][512]
// Spart: 1320448  (4194304) [16][512*512]
// total 5514752 floats = 22.06 MB

__global__ __launch_bounds__(256) void k_xbar(const float* __restrict__ x, float* __restrict__ xbar){
  int c = blockIdx.x, tid = threadIdx.x;
  float s = 0.f;
  for (int b = 0; b < BB; ++b){
    const float* px = x + ((size_t)(b*CC + c))*HWP;
    for (int p = tid; p < HWP; p += 256) s += px[p];
  }
  __shared__ float red[256];
  red[tid] = s; __syncthreads();
  for (int st = 128; st; st >>= 1){ if (tid < st) red[tid] += red[tid+st]; __syncthreads(); }
  if (tid == 0) xbar[c] = red[0] * (1.0f/ (float)NPIX);
}

__global__ __launch_bounds__(256) void k_gram(const float* __restrict__ x, float* __restrict__ Spart){
  __shared__ float xr[128*33];
  __shared__ float xc[128*33];
  int tid = threadIdx.x;
  int tile = blockIdx.x, b = blockIdx.y;
  int r0 = (tile >> 2)*128, c0 = (tile & 3)*128;
  int ti = tid >> 4, tj = tid & 15;
  float acc[8][8];
  #pragma unroll
  for (int i=0;i<8;++i)
    #pragma unroll
    for (int j=0;j<8;++j) acc[i][j]=0.f;
  for (int pk = 0; pk < HWP; pk += 32){
    __syncthreads();
    for (int t = tid; t < 4096; t += 256){
      int r = t >> 5, pp = t & 31;
      xr[r*33+pp] = x[(size_t)(b*CC + r0 + r)*HWP + pk + pp];
      xc[r*33+pp] = x[(size_t)(b*CC + c0 + r)*HWP + pk + pp];
    }
    __syncthreads();
    for (int pp = 0; pp < 32; ++pp){
      float a[8], bv[8];
      #pragma unroll
      for (int i=0;i<8;++i) a[i]  = xr[(i*16+ti)*33 + pp];
      #pragma unroll
      for (int j=0;j<8;++j) bv[j] = xc[(j*16+tj)*33 + pp];
      #pragma unroll
      for (int i=0;i<8;++i)
        #pragma unroll
        for (int j=0;j<8;++j) acc[i][j] = fmaf(a[i], bv[j], acc[i][j]);
    }
  }
  float* sp = Spart + (size_t)b*262144;
  #pragma unroll
  for (int i=0;i<8;++i)
    #pragma unroll
    for (int j=0;j<8;++j)
      sp[(r0 + i*16 + ti)*512 + c0 + j*16 + tj] = acc[i][j];
}

__global__ __launch_bounds__(256) void k_sreduce(const float* __restrict__ Spart, float* __restrict__ S){
  int i = blockIdx.x*256 + threadIdx.x;
  float s = 0.f;
  for (int k = 0; k < 16; ++k) s += Spart[(size_t)k*262144 + i];
  S[i] = s;
}

// G[i][j] = sum_c (wg[c][i]+eps)(wg[c][j]+eps)
__global__ __launch_bounds__(256) void k_G(const float* __restrict__ wg, float* __restrict__ G){
  int i = blockIdx.x, j = threadIdx.x;
  float s = 0.f;
  for (int c = 0; c < CC; ++c)
    s = fmaf(wg[c*DD + i] + 1e-8f, wg[c*DD + j] + 1e-8f, s);
  G[i*DD + j] = s;
}

__device__ __forceinline__ int rowst(int i){ return i*(2*DD + 1 - i)/2; } // i*(513-i)/2

__global__ __launch_bounds__(256) void k_chol(float* __restrict__ G){
  __shared__ float P[32896];
  int tid = threadIdx.x;
  for (int i = 0; i < DD; ++i){
    int base = rowst(i);
    for (int j = i + tid; j < DD; j += 256) P[base + j - i] = G[i*DD + j];
  }
  __syncthreads();
  for (int k = 0; k < DD; ++k){
    int bk = rowst(k);
    if (tid == 0) P[bk] = sqrtf(P[bk]);
    __syncthreads();
    float dk = P[bk];
    for (int j = k + 1 + tid; j < DD; j += 256) P[bk + j - k] /= dk;
    __syncthreads();
    int j = tid;
    if (j > k){
      float ukj = P[bk + j - k];
      for (int i = k + 1; i <= j; ++i)
        P[rowst(i) + j - i] -= P[bk + i - k] * ukj;
    }
    __syncthreads();
  }
  for (int i = 0; i < DD; ++i){
    int base = rowst(i);
    for (int j = i + tid; j < DD; j += 256) G[i*DD + j] = P[base + j - i];
  }
}

// Rt[j][l] = Rinv[l][j]  (back substitution, one column per thread)
__global__ __launch_bounds__(256) void k_rinv(const float* __restrict__ G, float* __restrict__ Rt){
  __shared__ float P[32896];
  int tid = threadIdx.x;
  for (int i = 0; i < DD; ++i){
    int base = rowst(i);
    for (int j = i + tid; j < DD; j += 256) P[base + j - i] = G[i*DD + j];
  }
  __syncthreads();
  int j = tid;
  float* col = Rt + (size_t)j*DD;
  for (int l = j + 1; l < DD; ++l) col[l] = 0.f;
  col[j] = 1.0f / P[rowst(j)];
  for (int i = j - 1; i >= 0; --i){
    int bi = rowst(i);
    float s = 0.f;
    for (int l = i + 1; l <= j; ++l) s = fmaf(P[bi + l - i], col[l], s);
    col[i] = -s / P[bi];
  }
}

// Q[c][j] = sum_{l<=j} A[c][l]*Rinv[l][j];  Qst[j][c] = Q[c][j]*inv_sqrt_c
__global__ __launch_bounds__(256) void k_Q(const float* __restrict__ wg, const float* __restrict__ Rt,
                                           float* __restrict__ Q, float* __restrict__ Qst){
  int c = blockIdx.x, j = threadIdx.x;
  __shared__ float arow[DD];
  arow[j] = wg[c*DD + j] + 1e-8f;
  __syncthreads();
  const float* rt = Rt + (size_t)j*DD;
  float q = 0.f;
  for (int l = 0; l <= j; ++l) q = fmaf(arow[l], rt[l], q);
  Q[c*DD + j] = q;
  Qst[j*CC + c] = q * INV_SQRT_C;
}

__global__ __launch_bounds__(256) void k_fold(const float* __restrict__ Wg, const float* __restrict__ Wc,
    const float* __restrict__ gamg, const float* __restrict__ betg,
    const float* __restrict__ gamc, const float* __restrict__ betc,
    const float* __restrict__ S, const float* __restrict__ xbar,
    float* __restrict__ Wgf, float* __restrict__ bgf,
    float* __restrict__ Wcf, float* __restrict__ bcf){
  int o = blockIdx.x & 511, br = blockIdx.x >> 9;
  int tid = threadIdx.x;
  const float* W = br ? Wc : Wg;
  __shared__ float wrow[512];
  __shared__ float red[256];
  __shared__ float red2[256];
  __shared__ float sc_s, bi_s;
  wrow[tid] = W[o*512 + tid]; wrow[tid+256] = W[o*512 + tid + 256];
  __syncthreads();
  float mp = 0.f;
  for (int c = tid; c < 512; c += 256) mp = fmaf(wrow[c], xbar[c], mp);
  float qp = 0.f;
  for (int c1 = tid; c1 < 512; c1 += 256){
    const float* srow = S + (size_t)c1*512;
    float y = 0.f;
    for (int c2 = 0; c2 < 512; ++c2) y = fmaf(srow[c2], wrow[c2], y);
    qp = fmaf(wrow[c1], y, qp);
  }
  red[tid] = mp; red2[tid] = qp; __syncthreads();
  for (int st = 128; st; st >>= 1){
    if (tid < st){ red[tid] += red[tid+st]; red2[tid] += red2[tid+st]; }
    __syncthreads();
  }
  if (tid == 0){
    float m = red[0];
    float E = red2[0] * (1.0f/(float)NPIX);
    float var = E - m*m;
    float rstd = rsqrtf(var + 1e-5f);
    float gma = br ? gamc[o] : gamg[o];
    float bta = br ? betc[o] : betg[o];
    sc_s = gma * rstd;
    bi_s = bta - gma * rstd * m;
  }
  __syncthreads();
  float* Wf = br ? Wcf : Wgf;
  float* bf = br ? bcf : bgf;
  Wf[o*512 + tid]     = sc_s * wrow[tid];
  Wf[o*512 + tid+256] = sc_s * wrow[tid+256];
  if (tid == 0) bf[o] = bi_s;
}

// gpart[b][slab][o] = sum over 256 pixels of relu(Wgf x + bgf)
__global__ __launch_bounds__(256) void k_gconv(const float* __restrict__ x,
    const float* __restrict__ Wf, const float* __restrict__ bf, float* __restrict__ gpart){
  __shared__ float wsm[64*65];
  __shared__ float xs[64*257];
  int tid = threadIdx.x;
  int slab = blockIdx.x, ot = blockIdx.y, b = blockIdx.z;
  int o0 = ot*64, p0 = slab*256;
  int to = tid >> 4, tp = tid & 15;
  float acc[4][16];
  #pragma unroll
  for (int i=0;i<4;++i)
    #pragma unroll
    for (int j=0;j<16;++j) acc[i][j]=0.f;
  for (int ck = 0; ck < 8; ++ck){
    int c0 = ck*64;
    __syncthreads();
    for (int t = tid; t < 4096; t += 256){
      int r = t >> 6, cc = t & 63;
      wsm[r*65 + cc] = Wf[(o0 + r)*512 + c0 + cc];
    }
    for (int t = tid; t < 16384; t += 256){
      int r = t >> 8, pp = t & 255;
      xs[r*257 + pp] = x[(size_t)(b*CC + c0 + r)*HWP + p0 + pp];
    }
    __syncthreads();
    for (int cc = 0; cc < 64; ++cc){
      float w[4];
      #pragma unroll
      for (int i=0;i<4;++i) w[i] = wsm[(to*4+i)*65 + cc];
      #pragma unroll
      for (int j=0;j<16;++j){
        float xv = xs[cc*257 + tp + j*16];
        #pragma unroll
        for (int i=0;i<4;++i) acc[i][j] = fmaf(w[i], xv, acc[i][j]);
      }
    }
  }
  __syncthreads();
  // bias + relu + sum over pixels; reduce across tp via wsm
  #pragma unroll
  for (int i=0;i<4;++i){
    float bb = bf[o0 + to*4 + i];
    float s = 0.f;
    #pragma unroll
    for (int j=0;j<16;++j) s += fmaxf(acc[i][j] + bb, 0.f);
    wsm[(to*4+i)*17 + tp] = s;
  }
  __syncthreads();
  if (tid < 64){
    float t = 0.f;
    for (int q = 0; q < 16; ++q) t += wsm[tid*17 + q];
    gpart[(size_t)(b*16 + slab)*512 + o0 + tid] = t;
  }
}

__global__ __launch_bounds__(256) void k_gvec(const float* __restrict__ gpart, const float* __restrict__ Q,
    const float* __restrict__ Qst, float* __restrict__ gvec){
  int b = blockIdx.x, tid = threadIdx.x;
  __shared__ float g0[512];
  __shared__ float aff[256];
  __shared__ float red[256];
  for (int o = tid; o < 512; o += 256){
    float s = 0.f;
    for (int sl = 0; sl < 16; ++sl) s += gpart[(size_t)(b*16 + sl)*512 + o];
    g0[o] = s * (1.0f/4096.0f);
  }
  __syncthreads();
  float l = 0.f;
  { const float* qr = Qst + (size_t)tid*512;
    for (int c = 0; c < 512; ++c) l = fmaf(qr[c], g0[c], l); }
  red[tid] = l; __syncthreads();
  for (int st = 128; st; st >>= 1){ if (tid < st) red[tid] = fmaxf(red[tid], red[tid+st]); __syncthreads(); }
  float m = red[0]; __syncthreads();
  float e = expf(l - m);
  red[tid] = e; __syncthreads();
  for (int st = 128; st; st >>= 1){ if (tid < st) red[tid] += red[tid+st]; __syncthreads(); }
  float inv = 1.0f/red[0];
  aff[tid] = e * inv;
  __syncthreads();
  for (int o = tid; o < 512; o += 256){
    const float* qr = Q + (size_t)o*DD;
    float v = 0.f;
    for (int d = 0; d < DD; ++d) v = fmaf(aff[d], qr[d], v);
    gvec[b*512 + o] = 1.0f/(1.0f + expf(-v));
  }
}

// fused channel branch: per block = (batch b, 32 pixels)
__global__ __launch_bounds__(256) void k_fused(const float* __restrict__ x,
    const float* __restrict__ Wcf, const float* __restrict__ bcf,
    const float* __restrict__ Qst, const float* __restrict__ Q,
    const float* __restrict__ gvec, float* __restrict__ out){
  __shared__ float Xs[16896];            // [512][33]; reused as 64x65 stage in ph2/ph4
  __shared__ __hip_bfloat16 Ts[17408];   // [512][34]
  __shared__ float Us[8224];             // [32][257]; ph1 W stage 64x65 fits
  int tid = threadIdx.x;
  int b = blockIdx.y, p0 = blockIdx.x*32;
  int to = tid >> 4, tp = tid & 15;

  for (int t = tid; t < 512*32; t += 256){
    int c = t >> 5, p = t & 31;
    Xs[c*33 + p] = x[(size_t)(b*CC + c)*HWP + p0 + p];
  }
  __syncthreads();

  // phase 1: t = relu(Wcf x + bcf) -> Ts (bf16)
  for (int ot = 0; ot < 8; ++ot){
    int o0 = ot*64;
    float acc[4][2] = {{0,0},{0,0},{0,0},{0,0}};
    for (int ck = 0; ck < 8; ++ck){
      int c0 = ck*64;
      __syncthreads();
      for (int t = tid; t < 4096; t += 256){
        int r = t >> 6, cc = t & 63;
        Us[r*65 + cc] = Wcf[(o0 + r)*512 + c0 + cc];
      }
      __syncthreads();
      for (int cc = 0; cc < 64; ++cc){
        float xv0 = Xs[(c0+cc)*33 + tp];
        float xv1 = Xs[(c0+cc)*33 + tp + 16];
        #pragma unroll
        for (int i=0;i<4;++i){
          float w = Us[(to*4+i)*65 + cc];
          acc[i][0] = fmaf(w, xv0, acc[i][0]);
          acc[i][1] = fmaf(w, xv1, acc[i][1]);
        }
      }
    }
    #pragma unroll
    for (int i=0;i<4;++i){
      int o = o0 + to*4 + i;
      float bb = bcf[o];
      Ts[o*34 + tp]      = __float2bfloat16(fmaxf(acc[i][0] + bb, 0.f));
      Ts[o*34 + tp + 16] = __float2bfloat16(fmaxf(acc[i][1] + bb, 0.f));
    }
  }
  __syncthreads();

  // phase 2: Us[p][d] = sum_o Ts[o][p]*Qst[d][o]
  for (int dt = 0; dt < 4; ++dt){
    int d0 = dt*64;
    float acc[4][2] = {{0,0},{0,0},{0,0},{0,0}};
    for (int ck = 0; ck < 8; ++ck){
      int o0 = ck*64;
      __syncthreads();
      for (int t = tid; t < 4096; t += 256){
        int r = t >> 6, oo = t & 63;
        Xs[r*65 + oo] = Qst[(d0 + r)*512 + o0 + oo];
      }
      __syncthreads();
      for (int oo = 0; oo < 64; ++oo){
        float t0 = __bfloat162float(Ts[(o0+oo)*34 + tp]);
        float t1 = __bfloat162float(Ts[(o0+oo)*34 + tp + 16]);
        #pragma unroll
        for (int i=0;i<4;++i){
          float q = Xs[(to*4+i)*65 + oo];
          acc[i][0] = fmaf(q, t0, acc[i][0]);
          acc[i][1] = fmaf(q, t1, acc[i][1]);
        }
      }
    }
    #pragma unroll
    for (int i=0;i<4;++i){
      Us[tp*257      + d0 + to*4 + i] = acc[i][0];
      Us[(tp+16)*257 + d0 + to*4 + i] = acc[i][1];
    }
  }
  __syncthreads();

  // phase 3: softmax over d per pixel (8 lanes/pixel)
  {
    int px = tid >> 3, sub = tid & 7;
    float m = -1e30f;
    for (int d = sub; d < 256; d += 8) m = fmaxf(m, Us[px*257 + d]);
    m = fmaxf(m, __shfl_xor(m, 1));
    m = fmaxf(m, __shfl_xor(m, 2));
    m = fmaxf(m, __shfl_xor(m, 4));
    float s = 0.f;
    for (int d = sub; d < 256; d += 8) s += expf(Us[px*257 + d] - m);
    s += __shfl_xor(s, 1);
    s += __shfl_xor(s, 2);
    s += __shfl_xor(s, 4);
    float inv = 1.0f/s;
    for (int d = sub; d < 256; d += 8) Us[px*257 + d] = expf(Us[px*257 + d] - m)*inv;
  }
  __syncthreads();

  // phase 4: out[o][p] = (sum_d Us[p][d]*Q[o][d]) * g[b][o] + x
  for (int ot = 0; ot < 8; ++ot){
    int o0 = ot*64;
    float acc[4][2] = {{0,0},{0,0},{0,0},{0,0}};
    for (int ck = 0; ck < 4; ++ck){
      int d0 = ck*64;
      __syncthreads();
      for (int t = tid; t < 4096; t += 256){
        int r = t >> 6, dd = t & 63;
        Xs[r*65 + dd] = Q[(o0 + r)*DD + d0 + dd];
      }
      __syncthreads();
      for (int dd = 0; dd < 64; ++dd){
        float a0 = Us[tp*257 + d0 + dd];
        float a1 = Us[(tp+16)*257 + d0 + dd];
        #pragma unroll
        for (int i=0;i<4;++i){
          float q = Xs[(to*4+i)*65 + dd];
          acc[i][0] = fmaf(q, a0, acc[i][0]);
          acc[i][1] = fmaf(q, a1, acc[i][1]);
        }
      }
    }
    #pragma unroll
    for (int i=0;i<4;++i){
      int o = o0 + to*4 + i;
      float gg = gvec[b*512 + o];
      int idx = (b*CC + o)*HWP + p0 + tp;
      out[idx]      = fmaf(acc[i][0], gg, x[idx]);
      out[idx + 16] = fmaf(acc[i][1], gg, x[idx + 16]);
    }
  }
}

extern "C" void kernel_launch(void* const* d_in, const int* in_sizes, int n_in,
                              void* d_out, int out_size, void* d_ws, size_t ws_size,
                              hipStream_t stream) {
  const float* x    = (const float*)d_in[0];
  const float* wg   = (const float*)d_in[1];
  const float* Wg   = (const float*)d_in[2];
  const float* gamg = (const float*)d_in[3];
  const float* betg = (const float*)d_in[4];
  const float* Wc   = (const float*)d_in[5];
  const float* gamc = (const float*)d_in[6];
  const float* betc = (const float*)d_in[7];
  float* out = (float*)d_out;

  float* ws = (float*)d_ws;
  float* G     = ws + 0;
  float* Rt    = ws + 65536;
  float* Q     = ws + 131072;
  float* Qst   = ws + 262144;
  float* S     = ws + 393216;
  float* xbar  = ws + 655360;
  float* Wgf   = ws + 655872;
  float* bgf   = ws + 918016;
  float* Wcf   = ws + 918528;
  float* bcf   = ws + 1180672;
  float* gvec  = ws + 1181184;
  float* gpart = ws + 1189376;
  float* Spart = ws + 1320448;

  k_xbar<<<512, 256, 0, stream>>>(x, xbar);
  k_gram<<<dim3(16,16), 256, 0, stream>>>(x, Spart);
  k_sreduce<<<1024, 256, 0, stream>>>(Spart, S);
  k_G<<<256, 256, 0, stream>>>(wg, G);
  k_chol<<<1, 256, 0, stream>>>(G);
  k_rinv<<<1, 256, 0, stream>>>(G, Rt);
  k_Q<<<512, 256, 0, stream>>>(wg, Rt, Q, Qst);
  k_fold<<<1024, 256, 0, stream>>>(Wg, Wc, gamg, betg, gamc, betc, S, xbar, Wgf, bgf, Wcf, bcf);
  k_gconv<<<dim3(16,8,16), 256, 0, stream>>>(x, Wgf, bgf, gpart);
  k_gvec<<<16, 256, 0, stream>>>(gpart, Q, Qst, gvec);
  k_fused<<<dim3(128,16), 256, 0, stream>>>(x, Wcf, bcf, Qst, Q, gvec, out);
}

// Round 2
// 3594.215 us; speedup vs baseline: 2.2730x; 2.2730x over previous
//
#include <hip/hip_runtime.h>
#include <hip/hip_bf16.h>

#define BB 16
#define CC 512
#define HWP 4096
#define DD 256
#define NPIX 65536
#define INV_SQRT_C 0.04419417382415922f

typedef unsigned short u16;
typedef __attribute__((ext_vector_type(8))) short s16x8;
typedef __attribute__((ext_vector_type(8))) unsigned short u16x8;
typedef __attribute__((ext_vector_type(4))) unsigned short u16x4;
typedef __attribute__((ext_vector_type(4))) float f32x4;

__device__ __forceinline__ u16 f2b(float f){
  unsigned int u = __builtin_bit_cast(unsigned int, f);
  unsigned int r = (u + 0x7fffu + ((u >> 16) & 1u)) >> 16;
  return (u16)r;
}

__device__ __forceinline__ f32x4 mfma16(s16x8 a, s16x8 b, f32x4 c){
  return __builtin_amdgcn_mfma_f32_16x16x32_bf16(a, b, c, 0, 0, 0);
}

// ---------------- ws layout ----------------
// floats: G 0 (65536) | Rt 65536 | Q 131072 (131072) | Qst 262144 (131072)
// S 393216 (262144) | xbar 655360 (512) | Wgf 655872 (262144) | bgf 918016 (512)
// Wcf 918528 (262144) | bcf 1180672 (512) | gvec 1181184 (8192)
// Spart 1320448 (4194304) | gpart 5514752 (524288)  -> end 6039040 floats
// u16 (base = ws+6039040 as u16*): Qb 0 (131072) | Qstb 131072 (131072)
// Wgb 262144 (262144) | Wcb 524288 (262144)  -> total ~25.7 MB

__global__ __launch_bounds__(256) void k_xbar(const float* __restrict__ x, float* __restrict__ xbar){
  int c = blockIdx.x, tid = threadIdx.x;
  float s = 0.f;
  for (int b = 0; b < BB; ++b){
    const float* px = x + ((size_t)(b*CC + c))*HWP;
    for (int p = tid; p < HWP; p += 256) s += px[p];
  }
  __shared__ float red[256];
  red[tid] = s; __syncthreads();
  for (int st = 128; st; st >>= 1){ if (tid < st) red[tid] += red[tid+st]; __syncthreads(); }
  if (tid == 0) xbar[c] = red[0] * (1.0f/ (float)NPIX);
}

// S = sum_b X_b X_b^T via MFMA bf16. tile 128x128, 8 waves (2x4), K=4096.
__global__ __launch_bounds__(512) void k_gram(const float* __restrict__ x, float* __restrict__ Spart){
  __shared__ __align__(16) u16 Asl[128*40];
  __shared__ __align__(16) u16 Bsl[128*40];
  int tid = threadIdx.x;
  int w = tid >> 6, lane = tid & 63, lr = lane & 15, g = lane >> 4;
  int tile = blockIdx.x, b = blockIdx.y;
  int r0 = (tile >> 2)*128, c0 = (tile & 3)*128;
  int wm = w >> 2, wn = w & 3;
  f32x4 acc[4][2] = {};
  const float* xb = x + (size_t)b*CC*HWP;
  for (int k0 = 0; k0 < HWP; k0 += 32){
    __syncthreads();
    for (int t = tid; t < 2048; t += 512){
      int arr = t >> 10;
      int row = (t >> 3) & 127;
      int q = t & 7;
      const float* src = xb + (size_t)((arr ? c0 : r0) + row)*HWP + k0 + q*4;
      f32x4 v = *(const f32x4*)src;
      u16x4 u; u[0]=f2b(v[0]); u[1]=f2b(v[1]); u[2]=f2b(v[2]); u[3]=f2b(v[3]);
      u16* dst = (arr ? Bsl : Asl) + row*40 + q*4;
      *(u16x4*)dst = u;
    }
    __syncthreads();
    s16x8 av[4], bv[2];
    #pragma unroll
    for (int mt = 0; mt < 4; ++mt) av[mt] = *(const s16x8*)&Asl[(wm*64 + mt*16 + lr)*40 + g*8];
    #pragma unroll
    for (int nt = 0; nt < 2; ++nt) bv[nt] = *(const s16x8*)&Bsl[(wn*32 + nt*16 + lr)*40 + g*8];
    #pragma unroll
    for (int mt = 0; mt < 4; ++mt)
      #pragma unroll
      for (int nt = 0; nt < 2; ++nt)
        acc[mt][nt] = mfma16(av[mt], bv[nt], acc[mt][nt]);
  }
  float* sp = Spart + (size_t)b*262144;
  #pragma unroll
  for (int mt = 0; mt < 4; ++mt)
    #pragma unroll
    for (int nt = 0; nt < 2; ++nt)
      #pragma unroll
      for (int r = 0; r < 4; ++r)
        sp[(size_t)(r0 + wm*64 + mt*16 + 4*g + r)*512 + c0 + wn*32 + nt*16 + lr] = acc[mt][nt][r];
}

__global__ __launch_bounds__(256) void k_sreduce(const float* __restrict__ Spart, float* __restrict__ S){
  int i = blockIdx.x*256 + threadIdx.x;
  float s = 0.f;
  for (int k = 0; k < 16; ++k) s += Spart[(size_t)k*262144 + i];
  S[i] = s;
}

__global__ __launch_bounds__(256) void k_G(const float* __restrict__ wg, float* __restrict__ G){
  int i = blockIdx.x, j = threadIdx.x;
  float s = 0.f;
  for (int c = 0; c < CC; ++c)
    s = fmaf(wg[c*DD + i] + 1e-8f, wg[c*DD + j] + 1e-8f, s);
  G[i*DD + j] = s;
}

__device__ __forceinline__ int rowst(int i){ return i*(2*DD + 1 - i)/2; }

__global__ __launch_bounds__(256) void k_chol(float* __restrict__ G){
  __shared__ float P[32896];
  int tid = threadIdx.x;
  for (int i = 0; i < DD; ++i){
    int base = rowst(i);
    for (int j = i + tid; j < DD; j += 256) P[base + j - i] = G[i*DD + j];
  }
  __syncthreads();
  for (int k = 0; k < DD; ++k){
    int bk = rowst(k);
    if (tid == 0) P[bk] = sqrtf(P[bk]);
    __syncthreads();
    float dk = P[bk];
    for (int j = k + 1 + tid; j < DD; j += 256) P[bk + j - k] /= dk;
    __syncthreads();
    int j = tid;
    if (j > k){
      float ukj = P[bk + j - k];
      for (int i = k + 1; i <= j; ++i)
        P[rowst(i) + j - i] -= P[bk + i - k] * ukj;
    }
    __syncthreads();
  }
  for (int i = 0; i < DD; ++i){
    int base = rowst(i);
    for (int j = i + tid; j < DD; j += 256) G[i*DD + j] = P[base + j - i];
  }
}

__global__ __launch_bounds__(256) void k_rinv(const float* __restrict__ G, float* __restrict__ Rt){
  __shared__ float P[32896];
  int tid = threadIdx.x;
  for (int i = 0; i < DD; ++i){
    int base = rowst(i);
    for (int j = i + tid; j < DD; j += 256) P[base + j - i] = G[i*DD + j];
  }
  __syncthreads();
  int j = tid;
  float* col = Rt + (size_t)j*DD;
  for (int l = j + 1; l < DD; ++l) col[l] = 0.f;
  col[j] = 1.0f / P[rowst(j)];
  for (int i = j - 1; i >= 0; --i){
    int bi = rowst(i);
    float s = 0.f;
    for (int l = i + 1; l <= j; ++l) s = fmaf(P[bi + l - i], col[l], s);
    col[i] = -s / P[bi];
  }
}

__global__ __launch_bounds__(256) void k_Q(const float* __restrict__ wg, const float* __restrict__ Rt,
                                           float* __restrict__ Q, float* __restrict__ Qst,
                                           u16* __restrict__ Qb, u16* __restrict__ Qstb){
  int c = blockIdx.x, j = threadIdx.x;
  __shared__ float arow[DD];
  arow[j] = wg[c*DD + j] + 1e-8f;
  __syncthreads();
  const float* rt = Rt + (size_t)j*DD;
  float q = 0.f;
  for (int l = 0; l <= j; ++l) q = fmaf(arow[l], rt[l], q);
  Q[c*DD + j] = q;
  Qst[j*CC + c] = q * INV_SQRT_C;
  Qb[c*DD + j] = f2b(q);
  Qstb[j*CC + c] = f2b(q * INV_SQRT_C);
}

__global__ __launch_bounds__(256) void k_fold(const float* __restrict__ Wg, const float* __restrict__ Wc,
    const float* __restrict__ gamg, const float* __restrict__ betg,
    const float* __restrict__ gamc, const float* __restrict__ betc,
    const float* __restrict__ S, const float* __restrict__ xbar,
    float* __restrict__ Wgf, float* __restrict__ bgf,
    float* __restrict__ Wcf, float* __restrict__ bcf,
    u16* __restrict__ Wgb, u16* __restrict__ Wcb){
  int o = blockIdx.x & 511, br = blockIdx.x >> 9;
  int tid = threadIdx.x;
  const float* W = br ? Wc : Wg;
  __shared__ float wrow[512];
  __shared__ float red[256];
  __shared__ float red2[256];
  __shared__ float sc_s, bi_s;
  wrow[tid] = W[o*512 + tid]; wrow[tid+256] = W[o*512 + tid + 256];
  __syncthreads();
  float mp = 0.f;
  for (int c = tid; c < 512; c += 256) mp = fmaf(wrow[c], xbar[c], mp);
  float qp = 0.f;
  for (int c1 = tid; c1 < 512; c1 += 256){
    const float* srow = S + (size_t)c1*512;
    float y = 0.f;
    for (int c2 = 0; c2 < 512; ++c2) y = fmaf(srow[c2], wrow[c2], y);
    qp = fmaf(wrow[c1], y, qp);
  }
  red[tid] = mp; red2[tid] = qp; __syncthreads();
  for (int st = 128; st; st >>= 1){
    if (tid < st){ red[tid] += red[tid+st]; red2[tid] += red2[tid+st]; }
    __syncthreads();
  }
  if (tid == 0){
    float m = red[0];
    float E = red2[0] * (1.0f/(float)NPIX);
    float var = E - m*m;
    float rstd = rsqrtf(var + 1e-5f);
    float gma = br ? gamc[o] : gamg[o];
    float bta = br ? betc[o] : betg[o];
    sc_s = gma * rstd;
    bi_s = bta - gma * rstd * m;
  }
  __syncthreads();
  float* Wf = br ? Wcf : Wgf;
  float* bf = br ? bcf : bgf;
  u16* Wb  = br ? Wcb : Wgb;
  float w0 = sc_s * wrow[tid], w1 = sc_s * wrow[tid+256];
  Wf[o*512 + tid]     = w0;
  Wf[o*512 + tid+256] = w1;
  Wb[o*512 + tid]     = f2b(w0);
  Wb[o*512 + tid+256] = f2b(w1);
  if (tid == 0) bf[o] = bi_s;
}

// global branch conv + relu + pooled partial sums, MFMA. block = (slab of 64 px, b)
__global__ __launch_bounds__(512) void k_gconv(const float* __restrict__ x,
    const u16* __restrict__ Wb, const float* __restrict__ bf, float* __restrict__ gpart){
  __shared__ __align__(16) u16 Xs[64*512];   // [p][c] bf16, swizzled
  int tid = threadIdx.x;
  int w = tid >> 6, lane = tid & 63, lr = lane & 15, g = lane >> 4;
  int slab = blockIdx.x, b = blockIdx.y;
  int p0 = slab*64;

  { // stage x -> Xs[p][c] bf16
    const float* xb = x + (size_t)b*CC*HWP + p0;
    int p = tid & 63;
    int c8 = (tid >> 6) * 8;
    for (int pass = 0; pass < 8; ++pass, c8 += 64){
      float v[8];
      #pragma unroll
      for (int i = 0; i < 8; ++i) v[i] = xb[(size_t)(c8 + i)*HWP + p];
      u16x8 u;
      #pragma unroll
      for (int i = 0; i < 8; ++i) u[i] = f2b(v[i]);
      *(u16x8*)&Xs[p*512 + (c8 ^ ((p & 7) << 3))] = u;
    }
  }
  __syncthreads();

  for (int i = 0; i < 4; ++i){
    int o0 = (w*4 + i)*16;
    f32x4 acc[4] = {};
    for (int k = 0; k < 16; ++k){
      int c0 = k*32 + g*8;
      s16x8 a = *(const s16x8*)(Wb + (size_t)(o0 + lr)*512 + c0);
      #pragma unroll
      for (int pt = 0; pt < 4; ++pt){
        int p = pt*16 + lr;
        s16x8 bv = *(const s16x8*)&Xs[p*512 + (c0 ^ ((p & 7) << 3))];
        acc[pt] = mfma16(a, bv, acc[pt]);
      }
    }
    f32x4 bias4 = *(const f32x4*)(bf + o0 + 4*g);
    float s[4] = {0.f, 0.f, 0.f, 0.f};
    #pragma unroll
    for (int pt = 0; pt < 4; ++pt)
      #pragma unroll
      for (int r = 0; r < 4; ++r)
        s[r] += fmaxf(acc[pt][r] + bias4[r], 0.f);
    #pragma unroll
    for (int r = 0; r < 4; ++r){
      s[r] += __shfl_xor(s[r], 1);
      s[r] += __shfl_xor(s[r], 2);
      s[r] += __shfl_xor(s[r], 4);
      s[r] += __shfl_xor(s[r], 8);
    }
    if (lr == 0){
      f32x4 sv; sv[0]=s[0]; sv[1]=s[1]; sv[2]=s[2]; sv[3]=s[3];
      *(f32x4*)(gpart + (size_t)(b*64 + slab)*512 + o0 + 4*g) = sv;
    }
  }
}

__global__ __launch_bounds__(256) void k_gvec(const float* __restrict__ gpart, const float* __restrict__ Q,
    const float* __restrict__ Qst, float* __restrict__ gvec){
  int b = blockIdx.x, tid = threadIdx.x;
  __shared__ float g0[512];
  __shared__ float aff[256];
  __shared__ float red[256];
  for (int o = tid; o < 512; o += 256){
    float s = 0.f;
    for (int sl = 0; sl < 64; ++sl) s += gpart[(size_t)(b*64 + sl)*512 + o];
    g0[o] = s * (1.0f/4096.0f);
  }
  __syncthreads();
  float l = 0.f;
  { const float* qr = Qst + (size_t)tid*512;
    for (int c = 0; c < 512; ++c) l = fmaf(qr[c], g0[c], l); }
  red[tid] = l; __syncthreads();
  for (int st = 128; st; st >>= 1){ if (tid < st) red[tid] = fmaxf(red[tid], red[tid+st]); __syncthreads(); }
  float m = red[0]; __syncthreads();
  float e = expf(l - m);
  red[tid] = e; __syncthreads();
  for (int st = 128; st; st >>= 1){ if (tid < st) red[tid] += red[tid+st]; __syncthreads(); }
  float inv = 1.0f/red[0];
  aff[tid] = e * inv;
  __syncthreads();
  for (int o = tid; o < 512; o += 256){
    const float* qr = Q + (size_t)o*DD;
    float v = 0.f;
    for (int d = 0; d < DD; ++d) v = fmaf(aff[d], qr[d], v);
    gvec[b*512 + o] = 1.0f/(1.0f + expf(-v));
  }
}

// fused channel branch, MFMA. block = (64 px, b), 8 waves.
__global__ __launch_bounds__(512) void k_fused(const float* __restrict__ x,
    const u16* __restrict__ Wcb, const float* __restrict__ bcf,
    const u16* __restrict__ Qstb, const u16* __restrict__ Qb,
    const float* __restrict__ gvec, float* __restrict__ out){
  __shared__ __align__(16) u16 Xs[64*512];   // [p][c] bf16; later Ls fp32 [64][256]
  __shared__ __align__(16) u16 Ts[64*512];   // [p][o] bf16; later As bf16 [64][256]
  float* Lsf = (float*)Xs;
  u16*   As  = Ts;
  int tid = threadIdx.x;
  int w = tid >> 6, lane = tid & 63, lr = lane & 15, g = lane >> 4;
  int b = blockIdx.y, p0 = blockIdx.x*64;

  { // stage x -> Xs[p][c] bf16
    const float* xb = x + (size_t)b*CC*HWP + p0;
    int p = tid & 63;
    int c8 = (tid >> 6) * 8;
    for (int pass = 0; pass < 8; ++pass, c8 += 64){
      float v[8];
      #pragma unroll
      for (int i = 0; i < 8; ++i) v[i] = xb[(size_t)(c8 + i)*HWP + p];
      u16x8 u;
      #pragma unroll
      for (int i = 0; i < 8; ++i) u[i] = f2b(v[i]);
      *(u16x8*)&Xs[p*512 + (c8 ^ ((p & 7) << 3))] = u;
    }
  }
  __syncthreads();

  // phase 1: T[o][p] = relu(Wc.X + b) -> Ts[p][o] bf16
  for (int i = 0; i < 4; ++i){
    int o0 = (w*4 + i)*16;
    f32x4 acc[4] = {};
    for (int k = 0; k < 16; ++k){
      int c0 = k*32 + g*8;
      s16x8 a = *(const s16x8*)(Wcb + (size_t)(o0 + lr)*512 + c0);
      #pragma unroll
      for (int pt = 0; pt < 4; ++pt){
        int p = pt*16 + lr;
        s16x8 bv = *(const s16x8*)&Xs[p*512 + (c0 ^ ((p & 7) << 3))];
        acc[pt] = mfma16(a, bv, acc[pt]);
      }
    }
    f32x4 bias4 = *(const f32x4*)(bcf + o0 + 4*g);
    #pragma unroll
    for (int pt = 0; pt < 4; ++pt){
      int p = pt*16 + lr;
      u16x4 u;
      #pragma unroll
      for (int r = 0; r < 4; ++r) u[r] = f2b(fmaxf(acc[pt][r] + bias4[r], 0.f));
      *(u16x4*)&Ts[p*512 + ((o0 + 4*g) ^ ((p & 7) << 3))] = u;
    }
  }
  __syncthreads();

  // phase 2: L[d][p] = Qst.T -> Ls[p][d] fp32 (overlays Xs)
  for (int i = 0; i < 2; ++i){
    int d0 = (w*2 + i)*16;
    f32x4 acc[4] = {};
    for (int k = 0; k < 16; ++k){
      int o0 = k*32 + g*8;
      s16x8 a = *(const s16x8*)(Qstb + (size_t)(d0 + lr)*512 + o0);
      #pragma unroll
      for (int pt = 0; pt < 4; ++pt){
        int p = pt*16 + lr;
        s16x8 bv = *(const s16x8*)&Ts[p*512 + (o0 ^ ((p & 7) << 3))];
        acc[pt] = mfma16(a, bv, acc[pt]);
      }
    }
    #pragma unroll
    for (int pt = 0; pt < 4; ++pt){
      int p = pt*16 + lr;
      *(f32x4*)&Lsf[p*256 + ((d0 + 4*g) ^ ((p & 7) << 2))] = acc[pt];
    }
  }
  __syncthreads();

  // phase 3: softmax over d per pixel -> As[p][d] bf16 (overlays Ts)
  {
    int px = tid >> 3, sub = tid & 7;
    float* Lrow = Lsf + px*256;
    int sw2 = (px & 7) << 2, sw3 = (px & 7) << 3;
    float v[32];
    #pragma unroll
    for (int j = 0; j < 8; ++j){
      int d0 = sub*32 + j*4;
      f32x4 t = *(const f32x4*)&Lrow[d0 ^ sw2];
      v[j*4+0] = t[0]; v[j*4+1] = t[1]; v[j*4+2] = t[2]; v[j*4+3] = t[3];
    }
    float m = v[0];
    #pragma unroll
    for (int j = 1; j < 32; ++j) m = fmaxf(m, v[j]);
    m = fmaxf(m, __shfl_xor(m, 1));
    m = fmaxf(m, __shfl_xor(m, 2));
    m = fmaxf(m, __shfl_xor(m, 4));
    float s = 0.f;
    #pragma unroll
    for (int j = 0; j < 32; ++j){ v[j] = __expf(v[j] - m); s += v[j]; }
    s += __shfl_xor(s, 1);
    s += __shfl_xor(s, 2);
    s += __shfl_xor(s, 4);
    float inv = 1.0f/s;
    #pragma unroll
    for (int jj = 0; jj < 4; ++jj){
      int d0 = sub*32 + jj*8;
      u16x8 u;
      #pragma unroll
      for (int i = 0; i < 8; ++i) u[i] = f2b(v[jj*8+i] * inv);
      *(u16x8*)&As[px*256 + (d0 ^ sw3)] = u;
    }
  }
  __syncthreads();

  // phase 4: ch[o][p] = Q.A ; out = ch*g + x
  for (int i = 0; i < 4; ++i){
    int o0 = (w*4 + i)*16;
    f32x4 acc[4] = {};
    for (int k = 0; k < 8; ++k){
      int d0 = k*32 + g*8;
      s16x8 a = *(const s16x8*)(Qb + (size_t)(o0 + lr)*256 + d0);
      #pragma unroll
      for (int pt = 0; pt < 4; ++pt){
        int p = pt*16 + lr;
        s16x8 bv = *(const s16x8*)&As[p*256 + (d0 ^ ((p & 7) << 3))];
        acc[pt] = mfma16(a, bv, acc[pt]);
      }
    }
    f32x4 gg = *(const f32x4*)(gvec + b*512 + o0 + 4*g);
    #pragma unroll
    for (int pt = 0; pt < 4; ++pt){
      #pragma unroll
      for (int r = 0; r < 4; ++r){
        size_t idx = (size_t)(b*CC + o0 + 4*g + r)*HWP + p0 + pt*16 + lr;
        out[idx] = fmaf(acc[pt][r], gg[r], x[idx]);
      }
    }
  }
}

extern "C" void kernel_launch(void* const* d_in, const int* in_sizes, int n_in,
                              void* d_out, int out_size, void* d_ws, size_t ws_size,
                              hipStream_t stream) {
  const float* x    = (const float*)d_in[0];
  const float* wg   = (const float*)d_in[1];
  const float* Wg   = (const float*)d_in[2];
  const float* gamg = (const float*)d_in[3];
  const float* betg = (const float*)d_in[4];
  const float* Wc   = (const float*)d_in[5];
  const float* gamc = (const float*)d_in[6];
  const float* betc = (const float*)d_in[7];
  float* out = (float*)d_out;

  float* ws = (float*)d_ws;
  float* G     = ws + 0;
  float* Rt    = ws + 65536;
  float* Q     = ws + 131072;
  float* Qst   = ws + 262144;
  float* S     = ws + 393216;
  float* xbar  = ws + 655360;
  float* Wgf   = ws + 655872;
  float* bgf   = ws + 918016;
  float* Wcf   = ws + 918528;
  float* bcf   = ws + 1180672;
  float* gvec  = ws + 1181184;
  float* Spart = ws + 1320448;
  float* gpart = ws + 5514752;
  u16*   ub    = (u16*)(ws + 6039040);
  u16* Qb   = ub;
  u16* Qstb = ub + 131072;
  u16* Wgb  = ub + 262144;
  u16* Wcb  = ub + 524288;

  k_xbar<<<512, 256, 0, stream>>>(x, xbar);
  k_gram<<<dim3(16,16), 512, 0, stream>>>(x, Spart);
  k_sreduce<<<1024, 256, 0, stream>>>(Spart, S);
  k_G<<<256, 256, 0, stream>>>(wg, G);
  k_chol<<<1, 256, 0, stream>>>(G);
  k_rinv<<<1, 256, 0, stream>>>(G, Rt);
  k_Q<<<512, 256, 0, stream>>>(wg, Rt, Q, Qst, Qb, Qstb);
  k_fold<<<1024, 256, 0, stream>>>(Wg, Wc, gamg, betg, gamc, betc, S, xbar, Wgf, bgf, Wcf, bcf, Wgb, Wcb);
  k_gconv<<<dim3(64,16), 512, 0, stream>>>(x, Wgb, bgf, gpart);
  k_gvec<<<16, 256, 0, stream>>>(gpart, Q, Qst, gvec);
  k_fused<<<dim3(64,16), 512, 0, stream>>>(x, Wcb, bcf, Qstb, Qb, gvec, out);
}